// Round 18
// baseline (299.039 us; speedup 1.0000x reference)
//
#include <hip/hip_runtime.h>

#define B_  8
#define S_  1024
#define D_  1024
#define H_  16
#define HD_ 64
#define M_  8192           // B*S
#define LOG2E 1.44269504088896f
#define QSCALE_ (0.125f * 1.44269504088896f)   // fold scale*log2e into Q
#define MSHIFT_ 20.0f      // static softmax shift (log2 domain)

typedef __attribute__((ext_vector_type(8))) short bf16x8;
typedef __attribute__((ext_vector_type(4))) float f32x4;

__device__ __forceinline__ unsigned short f2b(float x) {
  union { float f; unsigned u; } un; un.f = x;
  unsigned r = un.u + 0x7FFFu + ((un.u >> 16) & 1u);  // RNE
  return (unsigned short)(r >> 16);
}

// ---------------- kernel 0: hidden_states f32 -> bf16 ----------------
__global__ __launch_bounds__(256) void k_convert_x(const float* __restrict__ x,
                                                   unsigned short* __restrict__ o) {
  int i = (blockIdx.x * 256 + threadIdx.x) * 4;
  const int n = M_ * D_;
  const int stride = gridDim.x * 256 * 4;
  for (; i < n; i += stride) {
    const float4 v = *(const float4*)(x + i);
    ushort4 r;
    r.x = f2b(v.x); r.y = f2b(v.y); r.z = f2b(v.z); r.w = f2b(v.w);
    *(ushort4*)(o + i) = r;
  }
}

// ---------------- kernel 1: W (K x N) -> Wt bf16 (N x K), 3 matrices ----------------
__global__ __launch_bounds__(256) void k_transpose_w(const float* __restrict__ Wq,
    const float* __restrict__ Wk, const float* __restrict__ Wv,
    unsigned short* __restrict__ Wt) {
  __shared__ float t[64][65];
  const float* W = (blockIdx.z == 0) ? Wq : ((blockIdx.z == 1) ? Wk : Wv);
  unsigned short* dst = Wt + (size_t)blockIdx.z * (D_ * D_);
  const int k0 = blockIdx.x * 64, n0 = blockIdx.y * 64;
  const int tid = threadIdx.x;
#pragma unroll
  for (int i = 0; i < 16; ++i) {
    const int lin = i * 256 + tid;
    const int r = lin >> 6, c = lin & 63;
    t[r][c] = W[(size_t)(k0 + r) * D_ + n0 + c];
  }
  __syncthreads();
#pragma unroll
  for (int i = 0; i < 16; ++i) {
    const int lin = i * 256 + tid;
    const int r = lin >> 6, c = lin & 63;
    dst[(size_t)(n0 + r) * D_ + k0 + c] = f2b(t[c][r]);
  }
}

// ---------------- kernel 2: merged projection GEMM (m97 structure, 128x128x32) ----------------
__global__ __launch_bounds__(256) void k_proj(const unsigned short* __restrict__ X,
    const unsigned short* __restrict__ Wt,
    const float* __restrict__ bq, const float* __restrict__ bk, const float* __restrict__ bv,
    unsigned short* __restrict__ Qw, unsigned short* __restrict__ Kw,
    unsigned short* __restrict__ Vt) {
  __shared__ unsigned short xs[128 * 32];
  __shared__ unsigned short wsh[128 * 32];
  const int tid = threadIdx.x;
  const int lane = tid & 63, wv = tid >> 6;
  const int g = lane >> 4, li = lane & 15;
  const int m0 = blockIdx.x * 128;
  const int mode = (blockIdx.y >= 16);
  const int n0 = (mode ? (blockIdx.y - 16) : blockIdx.y) * 128;
  const int wr = wv >> 1, wc = wv & 1;
  const int wtrow0 = mode ? (2048 + n0) : n0;

  f32x4 acc[4][4];
#pragma unroll
  for (int i = 0; i < 4; ++i)
#pragma unroll
    for (int j = 0; j < 4; ++j) acc[i][j] = (f32x4){0.f, 0.f, 0.f, 0.f};

  const int srow = wv * 32 + (lane >> 2);
  const int skel = (lane & 3) * 8;

  for (int k0 = 0; k0 < D_; k0 += 32) {
#pragma unroll
    for (int i = 0; i < 2; ++i) {
      const unsigned short* gx = X + (size_t)(m0 + srow + i * 16) * D_ + k0 + skel;
      const unsigned short* gw = Wt + (size_t)(wtrow0 + srow + i * 16) * D_ + k0 + skel;
      __builtin_amdgcn_global_load_lds(
          (const __attribute__((address_space(1))) void*)gx,
          (__attribute__((address_space(3))) void*)&xs[(wv * 32 + i * 16) * 32], 16, 0, 0);
      __builtin_amdgcn_global_load_lds(
          (const __attribute__((address_space(1))) void*)gw,
          (__attribute__((address_space(3))) void*)&wsh[(wv * 32 + i * 16) * 32], 16, 0, 0);
    }
    __syncthreads();
    bf16x8 af[4], bfr[4];
#pragma unroll
    for (int i = 0; i < 4; ++i) {
      const int ar = wr * 64 + i * 16 + li;
      const int br = wc * 64 + i * 16 + li;
      if (!mode) {
        af[i]  = *(const bf16x8*)&xs[ar * 32 + g * 8];
        bfr[i] = *(const bf16x8*)&wsh[br * 32 + g * 8];
      } else {
        af[i]  = *(const bf16x8*)&wsh[ar * 32 + g * 8];
        bfr[i] = *(const bf16x8*)&xs[br * 32 + g * 8];
      }
    }
#pragma unroll
    for (int i = 0; i < 4; ++i)
#pragma unroll
      for (int j = 0; j < 4; ++j)
        acc[i][j] = __builtin_amdgcn_mfma_f32_16x16x32_bf16(af[i], bfr[j], acc[i][j], 0, 0, 0);
    __syncthreads();
  }

  if (!mode) {
#pragma unroll
    for (int j = 0; j < 4; ++j) {
      const int n = n0 + wc * 64 + j * 16 + li;
      const float bias = (n < D_) ? bq[n] : bk[n - D_];
#pragma unroll
      for (int i = 0; i < 4; ++i) {
#pragma unroll
        for (int r = 0; r < 4; ++r) {
          const int m = m0 + wr * 64 + i * 16 + g * 4 + r;
          const float v = acc[i][j][r] + bias;
          const int bb = m >> 10, ss = m & 1023;
          if (n < D_) {
            Qw[((size_t)(bb * H_ + (n >> 6)) * S_ + ss) * HD_ + (n & 63)] = f2b(v * QSCALE_);
          } else {
            const int nk = n - D_;
            Kw[((size_t)(bb * H_ + (nk >> 6)) * S_ + ss) * HD_ + (nk & 63)] = f2b(v);
          }
        }
      }
    }
  } else {
#pragma unroll
    for (int i = 0; i < 4; ++i) {
#pragma unroll
      for (int r = 0; r < 4; ++r) {
        const int nv = n0 + wr * 64 + i * 16 + g * 4 + r;
        const float bias = bv[nv];
#pragma unroll
        for (int j = 0; j < 4; ++j) {
          const int m = m0 + wc * 64 + j * 16 + li;
          const int bb = m >> 10, ss = m & 1023;
          const float v = acc[i][j][r] + bias;
          Vt[((size_t)(bb * H_ + (nv >> 6)) * HD_ + (nv & 63)) * S_ + ss] = f2b(v);
        }
      }
    }
  }
}

// ---------------- kernel 3: flash attention — R15 pipeline, QBLK=128 (8 waves) ----------------
// Single change vs R15 (268us best): block covers 128 q-rows (512 threads, 8 waves),
// halving the per-CU K/V re-stage stream (each K/V tile now amortized over 128 q).
// Per wave per phase: K 1 DMA + V 1 DMA + prev 4 DMA + mask 4 reg loads = 10 VMEM
// -> vmcnt(10). Each wave's compute is byte-identical to R15 (16 q-rows each).
// LDS 114 KB -> 1 block/CU, 8 waves (same wave count as R15's 2x4).
__global__ __launch_bounds__(512, 1) void k_attn(const unsigned short* __restrict__ Qw,
    const unsigned short* __restrict__ Kw, const unsigned short* __restrict__ Vt,
    const float* __restrict__ prev, const float* __restrict__ mask,
    float* __restrict__ out) {
  __shared__ unsigned short k_s[2][4096];       // [buf] 64 kv x 64 d, swizzled chunks, 8 KB/buf
  __shared__ unsigned short v_s[2][4096];       // [buf] 64 d x 64 kv, swizzled chunks, 8 KB/buf
  __shared__ float pm_s[2][8][1024];            // [buf][wave] 16 q x 64 kv f32, swizzled, 32 KB/buf
  __shared__ unsigned short p_lds[8][16][72];   // P bounce (q-row major), 144B rows, 18 KB
  const int tid = threadIdx.x;
  const int lane = tid & 63, wv = tid >> 6;     // wv 0..7
  const int g = lane >> 4, li = lane & 15;

  const int phys = blockIdx.x + 8 * blockIdx.y;   // 0..1023
  const int xcd = phys & 7, idx = phys >> 3;      // idx 0..127
  const int qt = idx & 7;                         // consecutive same-XCD blocks: same bh
  const int bh = xcd + 8 * (idx >> 3);            // 0..127
  const int b = bh >> 4, h = bh & 15;
  const int q0 = qt * 128 + wv * 16;              // this wave's 16 q-rows

  const unsigned short* kbase = Kw + (size_t)bh * S_ * HD_;
  const unsigned short* vbase = Vt + (size_t)bh * HD_ * S_;
  const float* pbase = prev + (size_t)bh * S_ * S_ + (size_t)q0 * S_;  // wave's q-slice
  const float* mb    = mask + (size_t)b * S_ * S_ + (size_t)(q0 + li) * S_ + g * 4;

  // Q fragment (B-operand; col=li=q, k=g*8+e=d), pre-scaled by SCALE*LOG2E
  bf16x8 qf[2];
  {
    const unsigned short* qp = Qw + ((size_t)bh * S_ + q0 + li) * HD_ + g * 8;
    qf[0] = *(const bf16x8*)qp;
    qf[1] = *(const bf16x8*)(qp + 32);
  }

  // K/V DMA: 1 DMA/wave = 8 consecutive rows x 128B (1KB contiguous); lane l ->
  // row group rloc8 = l>>3, chunk (l&7)^rloc8 (XOR permutes within the row).
  const int rloc8 = lane >> 3;
  const int csw8  = (((lane & 7) ^ rloc8) << 3);   // ushort offset of swizzled 16B chunk
  // prev DMA: 4 DMA/wave x 4 rows x 256B; lane l -> row i*4 + (l>>4), chunk (l&15)^(row&7).
  const int prow4 = lane >> 4;
  const int pchnk = lane & 15;

  // 6 global_load_lds + 4 mask VGPR loads per phase per wave = 10 VMEM
#define STAGE(TN, BI)                                                                      \
  {                                                                                        \
    const int sn = (TN) * 64;                                                              \
    const int krow = wv * 8 + rloc8;                                                       \
    __builtin_amdgcn_global_load_lds(                                                      \
        (const __attribute__((address_space(1))) void*)(kbase + (size_t)(sn + krow) * HD_ + csw8), \
        (__attribute__((address_space(3))) void*)(&k_s[BI][0] + wv * 512), 16, 0, 0);      \
    __builtin_amdgcn_global_load_lds(                                                      \
        (const __attribute__((address_space(1))) void*)(vbase + (size_t)krow * S_ + sn + csw8), \
        (__attribute__((address_space(3))) void*)(&v_s[BI][0] + wv * 512), 16, 0, 0);      \
    _Pragma("unroll")                                                                      \
    for (int i = 0; i < 4; ++i) {                                                          \
      const int row = i * 4 + prow4;                                                       \
      __builtin_amdgcn_global_load_lds(                                                    \
          (const __attribute__((address_space(1))) void*)(pbase + (size_t)row * S_ + sn + ((pchnk ^ (row & 7)) << 2)), \
          (__attribute__((address_space(3))) void*)(&pm_s[BI][wv][i * 256]), 16, 0, 0);    \
    }                                                                                      \
  }

  float lrun = 0.f;
  f32x4 ctx[4];
#pragma unroll
  for (int d = 0; d < 4; ++d) ctx[d] = (f32x4){0.f, 0.f, 0.f, 0.f};

  f32x4 mA[4], mB[4];

  // prologue: stage tile 0 + mask(0)  (10 VMEM ops, not waited here)
  STAGE(0, 0);
#pragma unroll
  for (int cb = 0; cb < 4; ++cb) mA[cb] = *(const f32x4*)(mb + cb * 16);

  // Phase: STAGE(t+1,NB) + mask(t+1) [10 ops] -> vmcnt(10) -> barrier ->
  // compute(buf PB, MCUR) -> barrier (WAR).
#define PHASE(T, PB, NB, MCUR, MNXT)                                                  \
  {                                                                                   \
    const int tn = ((T) < 15) ? (T) + 1 : 15;                                         \
    STAGE(tn, NB);                                                                    \
    _Pragma("unroll")                                                                 \
    for (int cb = 0; cb < 4; ++cb)                                                    \
      MNXT[cb] = *(const f32x4*)(mb + tn * 64 + cb * 16);                             \
    asm volatile("s_waitcnt vmcnt(10)" ::: "memory");                                 \
    __builtin_amdgcn_s_barrier();                                                     \
    {                                                                                 \
      const unsigned short* kb = &k_s[PB][0];                                         \
      const unsigned short* vb = &v_s[PB][0];                                         \
      const float* pmw = &pm_s[PB][wv][0];                                            \
      f32x4 sa[4];                                                                    \
      _Pragma("unroll")                                                               \
      for (int cb = 0; cb < 4; ++cb) {                                                \
        const int r = cb * 16 + li;                                                   \
        const bf16x8 k0 = *(const bf16x8*)(kb + r * 64 + ((g ^ (li & 7)) << 3));      \
        const bf16x8 k1 = *(const bf16x8*)(kb + r * 64 + (((4 + g) ^ (li & 7)) << 3)); \
        f32x4 z = (f32x4){0.f, 0.f, 0.f, 0.f};                                        \
        z      = __builtin_amdgcn_mfma_f32_16x16x32_bf16(k0, qf[0], z, 0, 0, 0);      \
        sa[cb] = __builtin_amdgcn_mfma_f32_16x16x32_bf16(k1, qf[1], z, 0, 0, 0);      \
      }                                                                               \
      _Pragma("unroll")                                                               \
      for (int cb = 0; cb < 4; ++cb) {                                                \
        const f32x4 pv = *(const f32x4*)(pmw + li * 64 + (((cb * 4 + g) ^ (li & 7)) << 2)); \
        f32x4 pmc;                                                                    \
        pmc.x = fmaf(pv.x + MCUR[cb].x, LOG2E, -MSHIFT_);                             \
        pmc.y = fmaf(pv.y + MCUR[cb].y, LOG2E, -MSHIFT_);                             \
        pmc.z = fmaf(pv.z + MCUR[cb].z, LOG2E, -MSHIFT_);                             \
        pmc.w = fmaf(pv.w + MCUR[cb].w, LOG2E, -MSHIFT_);                             \
        const float e0 = exp2f(sa[cb][0] + pmc.x);                                    \
        const float e1 = exp2f(sa[cb][1] + pmc.y);                                    \
        const float e2 = exp2f(sa[cb][2] + pmc.z);                                    \
        const float e3 = exp2f(sa[cb][3] + pmc.w);                                    \
        lrun += (e0 + e1) + (e2 + e3);                                                \
        ushort4 pw;                                                                   \
        pw.x = f2b(e0); pw.y = f2b(e1); pw.z = f2b(e2); pw.w = f2b(e3);               \
        *(ushort4*)&p_lds[wv][li][cb * 16 + g * 4] = pw;                              \
      }                                                                               \
      bf16x8 pf0 = *(const bf16x8*)&p_lds[wv][li][g * 8];                             \
      bf16x8 pf1 = *(const bf16x8*)&p_lds[wv][li][32 + g * 8];                        \
      _Pragma("unroll")                                                               \
      for (int d = 0; d < 4; ++d) {                                                   \
        const int r = d * 16 + li;                                                    \
        const bf16x8 v0 = *(const bf16x8*)(vb + r * 64 + ((g ^ (li & 7)) << 3));      \
        const bf16x8 v1 = *(const bf16x8*)(vb + r * 64 + (((4 + g) ^ (li & 7)) << 3)); \
        ctx[d] = __builtin_amdgcn_mfma_f32_16x16x32_bf16(pf0, v0, ctx[d], 0, 0, 0);   \
        ctx[d] = __builtin_amdgcn_mfma_f32_16x16x32_bf16(pf1, v1, ctx[d], 0, 0, 0);   \
      }                                                                               \
    }                                                                                 \
    __builtin_amdgcn_s_barrier();                                                     \
  }

  for (int t = 0; t < 16; t += 2) {
    PHASE(t,     0, 1, mA, mB);
    PHASE(t + 1, 1, 0, mB, mA);
  }
#undef PHASE
#undef STAGE

  // drain the redundant tail STAGE before LDS deallocation at wave exit
  asm volatile("s_waitcnt vmcnt(0)" ::: "memory");

  // row sums: combine the 4 g-groups (lane li holds partial for q-row li)
  lrun += __shfl_xor(lrun, 16);
  lrun += __shfl_xor(lrun, 32);
#pragma unroll
  for (int j2 = 0; j2 < 4; ++j2) {
    const float rs = __shfl(lrun, g * 4 + j2);
    const float inv = 1.0f / rs;
    const int q = q0 + g * 4 + j2;
    float* op = out + ((size_t)b * S_ + q) * D_ + h * HD_ + li;
#pragma unroll
    for (int d = 0; d < 4; ++d)
      op[d * 16] = ctx[d][j2] * inv;
  }
}

extern "C" void kernel_launch(void* const* d_in, const int* in_sizes, int n_in,
                              void* d_out, int out_size, void* d_ws, size_t ws_size,
                              hipStream_t stream) {
  const float* hs   = (const float*)d_in[0];
  const float* mask = (const float*)d_in[1];
  const float* prev = (const float*)d_in[2];
  const float* Wq   = (const float*)d_in[3];
  const float* bq   = (const float*)d_in[4];
  const float* Wk   = (const float*)d_in[5];
  const float* bk   = (const float*)d_in[6];
  const float* Wv   = (const float*)d_in[7];
  const float* bv   = (const float*)d_in[8];
  float* out = (float*)d_out;

  char* ws = (char*)d_ws;
  unsigned short* Xbf = (unsigned short*)ws;                    // 16 MB
  unsigned short* Wt  = (unsigned short*)(ws + (16ull << 20));  //  6 MB
  unsigned short* Qw  = (unsigned short*)(ws + (22ull << 20));  // 16 MB
  unsigned short* Kw  = (unsigned short*)(ws + (38ull << 20));  // 16 MB
  unsigned short* Vt  = (unsigned short*)(ws + (54ull << 20));  // 16 MB  (total 70 MB)

  k_convert_x<<<2048, 256, 0, stream>>>(hs, Xbf);
  k_transpose_w<<<dim3(16, 16, 3), 256, 0, stream>>>(Wq, Wk, Wv, Wt);
  k_proj<<<dim3(64, 24), 256, 0, stream>>>(Xbf, Wt, bq, bk, bv, Qw, Kw, Vt);
  k_attn<<<dim3(8, 128), 512, 0, stream>>>(Qw, Kw, Vt, prev, mask, out);
}

// Round 19
// 271.365 us; speedup vs baseline: 1.1020x; 1.1020x over previous
//
#include <hip/hip_runtime.h>

#define B_  8
#define S_  1024
#define D_  1024
#define H_  16
#define HD_ 64
#define M_  8192           // B*S
#define LOG2E 1.44269504088896f
#define QSCALE_ (0.125f * 1.44269504088896f)   // fold scale*log2e into Q
#define MSHIFT_ 20.0f      // static softmax shift (log2 domain)

typedef __attribute__((ext_vector_type(8))) short bf16x8;
typedef __attribute__((ext_vector_type(4))) float f32x4;

__device__ __forceinline__ unsigned short f2b(float x) {
  union { float f; unsigned u; } un; un.f = x;
  unsigned r = un.u + 0x7FFFu + ((un.u >> 16) & 1u);  // RNE
  return (unsigned short)(r >> 16);
}

// ---------------- kernel 0: hidden_states f32 -> bf16 ----------------
__global__ __launch_bounds__(256) void k_convert_x(const float* __restrict__ x,
                                                   unsigned short* __restrict__ o) {
  int i = (blockIdx.x * 256 + threadIdx.x) * 4;
  const int n = M_ * D_;
  const int stride = gridDim.x * 256 * 4;
  for (; i < n; i += stride) {
    const float4 v = *(const float4*)(x + i);
    ushort4 r;
    r.x = f2b(v.x); r.y = f2b(v.y); r.z = f2b(v.z); r.w = f2b(v.w);
    *(ushort4*)(o + i) = r;
  }
}

// ---------------- kernel 1: W (K x N) -> Wt bf16 (N x K), 3 matrices ----------------
__global__ __launch_bounds__(256) void k_transpose_w(const float* __restrict__ Wq,
    const float* __restrict__ Wk, const float* __restrict__ Wv,
    unsigned short* __restrict__ Wt) {
  __shared__ float t[64][65];
  const float* W = (blockIdx.z == 0) ? Wq : ((blockIdx.z == 1) ? Wk : Wv);
  unsigned short* dst = Wt + (size_t)blockIdx.z * (D_ * D_);
  const int k0 = blockIdx.x * 64, n0 = blockIdx.y * 64;
  const int tid = threadIdx.x;
#pragma unroll
  for (int i = 0; i < 16; ++i) {
    const int lin = i * 256 + tid;
    const int r = lin >> 6, c = lin & 63;
    t[r][c] = W[(size_t)(k0 + r) * D_ + n0 + c];
  }
  __syncthreads();
#pragma unroll
  for (int i = 0; i < 16; ++i) {
    const int lin = i * 256 + tid;
    const int r = lin >> 6, c = lin & 63;
    dst[(size_t)(n0 + r) * D_ + k0 + c] = f2b(t[c][r]);
  }
}

// ---------------- kernel 2: merged projection GEMM (m97 structure, 128x128x32) ----------------
__global__ __launch_bounds__(256) void k_proj(const unsigned short* __restrict__ X,
    const unsigned short* __restrict__ Wt,
    const float* __restrict__ bq, const float* __restrict__ bk, const float* __restrict__ bv,
    unsigned short* __restrict__ Qw, unsigned short* __restrict__ Kw,
    unsigned short* __restrict__ Vt) {
  __shared__ unsigned short xs[128 * 32];
  __shared__ unsigned short wsh[128 * 32];
  const int tid = threadIdx.x;
  const int lane = tid & 63, wv = tid >> 6;
  const int g = lane >> 4, li = lane & 15;
  const int m0 = blockIdx.x * 128;
  const int mode = (blockIdx.y >= 16);
  const int n0 = (mode ? (blockIdx.y - 16) : blockIdx.y) * 128;
  const int wr = wv >> 1, wc = wv & 1;
  const int wtrow0 = mode ? (2048 + n0) : n0;

  f32x4 acc[4][4];
#pragma unroll
  for (int i = 0; i < 4; ++i)
#pragma unroll
    for (int j = 0; j < 4; ++j) acc[i][j] = (f32x4){0.f, 0.f, 0.f, 0.f};

  const int srow = wv * 32 + (lane >> 2);
  const int skel = (lane & 3) * 8;

  for (int k0 = 0; k0 < D_; k0 += 32) {
#pragma unroll
    for (int i = 0; i < 2; ++i) {
      const unsigned short* gx = X + (size_t)(m0 + srow + i * 16) * D_ + k0 + skel;
      const unsigned short* gw = Wt + (size_t)(wtrow0 + srow + i * 16) * D_ + k0 + skel;
      __builtin_amdgcn_global_load_lds(
          (const __attribute__((address_space(1))) void*)gx,
          (__attribute__((address_space(3))) void*)&xs[(wv * 32 + i * 16) * 32], 16, 0, 0);
      __builtin_amdgcn_global_load_lds(
          (const __attribute__((address_space(1))) void*)gw,
          (__attribute__((address_space(3))) void*)&wsh[(wv * 32 + i * 16) * 32], 16, 0, 0);
    }
    __syncthreads();
    bf16x8 af[4], bfr[4];
#pragma unroll
    for (int i = 0; i < 4; ++i) {
      const int ar = wr * 64 + i * 16 + li;
      const int br = wc * 64 + i * 16 + li;
      if (!mode) {
        af[i]  = *(const bf16x8*)&xs[ar * 32 + g * 8];
        bfr[i] = *(const bf16x8*)&wsh[br * 32 + g * 8];
      } else {
        af[i]  = *(const bf16x8*)&wsh[ar * 32 + g * 8];
        bfr[i] = *(const bf16x8*)&xs[br * 32 + g * 8];
      }
    }
#pragma unroll
    for (int i = 0; i < 4; ++i)
#pragma unroll
      for (int j = 0; j < 4; ++j)
        acc[i][j] = __builtin_amdgcn_mfma_f32_16x16x32_bf16(af[i], bfr[j], acc[i][j], 0, 0, 0);
    __syncthreads();
  }

  if (!mode) {
#pragma unroll
    for (int j = 0; j < 4; ++j) {
      const int n = n0 + wc * 64 + j * 16 + li;
      const float bias = (n < D_) ? bq[n] : bk[n - D_];
#pragma unroll
      for (int i = 0; i < 4; ++i) {
#pragma unroll
        for (int r = 0; r < 4; ++r) {
          const int m = m0 + wr * 64 + i * 16 + g * 4 + r;
          const float v = acc[i][j][r] + bias;
          const int bb = m >> 10, ss = m & 1023;
          if (n < D_) {
            Qw[((size_t)(bb * H_ + (n >> 6)) * S_ + ss) * HD_ + (n & 63)] = f2b(v * QSCALE_);
          } else {
            const int nk = n - D_;
            Kw[((size_t)(bb * H_ + (nk >> 6)) * S_ + ss) * HD_ + (nk & 63)] = f2b(v);
          }
        }
      }
    }
  } else {
#pragma unroll
    for (int i = 0; i < 4; ++i) {
#pragma unroll
      for (int r = 0; r < 4; ++r) {
        const int nv = n0 + wr * 64 + i * 16 + g * 4 + r;
        const float bias = bv[nv];
#pragma unroll
        for (int j = 0; j < 4; ++j) {
          const int m = m0 + wc * 64 + j * 16 + li;
          const int bb = m >> 10, ss = m & 1023;
          const float v = acc[i][j][r] + bias;
          Vt[((size_t)(bb * H_ + (nv >> 6)) * HD_ + (nv & 63)) * S_ + ss] = f2b(v);
        }
      }
    }
  }
}

// ---------------- kernel 3: flash attention — R15 pipeline verbatim + s_setprio (T5) ----------------
// Exact R15 (268us best). Single addition: setprio(1)/setprio(0) around the QK and PV
// MFMA clusters — with 2 independent blocks/CU at different phases, the CU scheduler
// can favor the MFMA-entering waves (guide m191: attn +4-7%, within-probe).
__global__ __launch_bounds__(256, 2) void k_attn(const unsigned short* __restrict__ Qw,
    const unsigned short* __restrict__ Kw, const unsigned short* __restrict__ Vt,
    const float* __restrict__ prev, const float* __restrict__ mask,
    float* __restrict__ out) {
  __shared__ unsigned short k_s[2][4096];       // [buf] 64 kv x 64 d, swizzled chunks, 8 KB/buf
  __shared__ unsigned short v_s[2][4096];       // [buf] 64 d x 64 kv, swizzled chunks, 8 KB/buf
  __shared__ float pm_s[2][4][1024];            // [buf][wave] 16 q x 64 kv f32, swizzled, 16 KB/buf
  __shared__ unsigned short p_lds[4][16][72];   // P bounce (q-row major), 144B rows, 9 KB
  const int tid = threadIdx.x;
  const int lane = tid & 63, wv = tid >> 6;
  const int g = lane >> 4, li = lane & 15;

  const int phys = blockIdx.x + 16 * blockIdx.y;  // 0..2047
  const int xcd = phys & 7, idx = phys >> 3;
  const int qt = idx & 15;                        // consecutive same-XCD blocks: same bh
  const int bh = xcd + 8 * (idx >> 4);
  const int b = bh >> 4, h = bh & 15;
  const int q0 = qt * 64 + wv * 16;

  const unsigned short* kbase = Kw + (size_t)bh * S_ * HD_;
  const unsigned short* vbase = Vt + (size_t)bh * HD_ * S_;
  const float* pbase = prev + (size_t)bh * S_ * S_ + (size_t)q0 * S_;  // wave's q-slice
  const float* mb    = mask + (size_t)b * S_ * S_ + (size_t)(q0 + li) * S_ + g * 4;

  // Q fragment (B-operand; col=li=q, k=g*8+e=d), pre-scaled by SCALE*LOG2E
  bf16x8 qf[2];
  {
    const unsigned short* qp = Qw + ((size_t)bh * S_ + q0 + li) * HD_ + g * 8;
    qf[0] = *(const bf16x8*)qp;
    qf[1] = *(const bf16x8*)(qp + 32);
  }

  // K/V DMA: per DMA 8 consecutive rows x 128B (1KB contiguous); lane l -> row
  // group rloc8 = l>>3, chunk (l&7)^rloc8 (XOR permutes within the row).
  const int rloc8 = lane >> 3;
  const int csw8  = (((lane & 7) ^ rloc8) << 3);   // ushort offset of swizzled 16B chunk
  // prev DMA: per DMA 4 rows x 256B; lane l -> row i*4 + (l>>4), chunk (l&15)^(row&7).
  const int prow4 = lane >> 4;
  const int pchnk = lane & 15;

  // 8 global_load_lds + 4 mask VGPR loads per phase per wave = 12 VMEM
#define STAGE(TN, BI)                                                                      \
  {                                                                                        \
    const int sn = (TN) * 64;                                                              \
    _Pragma("unroll")                                                                      \
    for (int i = 0; i < 2; ++i) {                                                          \
      const int row = wv * 16 + i * 8 + rloc8;                                             \
      __builtin_amdgcn_global_load_lds(                                                    \
          (const __attribute__((address_space(1))) void*)(kbase + (size_t)(sn + row) * HD_ + csw8), \
          (__attribute__((address_space(3))) void*)(&k_s[BI][0] + (wv * 16 + i * 8) * 64), 16, 0, 0); \
      __builtin_amdgcn_global_load_lds(                                                    \
          (const __attribute__((address_space(1))) void*)(vbase + (size_t)row * S_ + sn + csw8), \
          (__attribute__((address_space(3))) void*)(&v_s[BI][0] + (wv * 16 + i * 8) * 64), 16, 0, 0); \
    }                                                                                      \
    _Pragma("unroll")                                                                      \
    for (int i = 0; i < 4; ++i) {                                                          \
      const int row = i * 4 + prow4;                                                       \
      __builtin_amdgcn_global_load_lds(                                                    \
          (const __attribute__((address_space(1))) void*)(pbase + (size_t)row * S_ + sn + ((pchnk ^ (row & 7)) << 2)), \
          (__attribute__((address_space(3))) void*)(&pm_s[BI][wv][i * 256]), 16, 0, 0);    \
    }                                                                                      \
  }

  float lrun = 0.f;
  f32x4 ctx[4];
#pragma unroll
  for (int d = 0; d < 4; ++d) ctx[d] = (f32x4){0.f, 0.f, 0.f, 0.f};

  f32x4 mA[4], mB[4];

  // prologue: stage tile 0 + mask(0)  (12 VMEM ops, not waited here)
  STAGE(0, 0);
#pragma unroll
  for (int cb = 0; cb < 4; ++cb) mA[cb] = *(const f32x4*)(mb + cb * 16);

  // Phase: STAGE(t+1,NB) + mask(t+1) [12 ops] -> vmcnt(12) [prev phase's 12 done,
  // current 12 stay in flight] -> barrier -> compute(buf PB, MCUR) -> barrier (WAR).
#define PHASE(T, PB, NB, MCUR, MNXT)                                                  \
  {                                                                                   \
    const int tn = ((T) < 15) ? (T) + 1 : 15;                                         \
    STAGE(tn, NB);                                                                    \
    _Pragma("unroll")                                                                 \
    for (int cb = 0; cb < 4; ++cb)                                                    \
      MNXT[cb] = *(const f32x4*)(mb + tn * 64 + cb * 16);                             \
    asm volatile("s_waitcnt vmcnt(12)" ::: "memory");                                 \
    __builtin_amdgcn_s_barrier();                                                     \
    {                                                                                 \
      const unsigned short* kb = &k_s[PB][0];                                         \
      const unsigned short* vb = &v_s[PB][0];                                         \
      const float* pmw = &pm_s[PB][wv][0];                                            \
      f32x4 sa[4];                                                                    \
      __builtin_amdgcn_s_setprio(1);                                                  \
      _Pragma("unroll")                                                               \
      for (int cb = 0; cb < 4; ++cb) {                                                \
        const int r = cb * 16 + li;                                                   \
        const bf16x8 k0 = *(const bf16x8*)(kb + r * 64 + ((g ^ (li & 7)) << 3));      \
        const bf16x8 k1 = *(const bf16x8*)(kb + r * 64 + (((4 + g) ^ (li & 7)) << 3)); \
        f32x4 z = (f32x4){0.f, 0.f, 0.f, 0.f};                                        \
        z      = __builtin_amdgcn_mfma_f32_16x16x32_bf16(k0, qf[0], z, 0, 0, 0);      \
        sa[cb] = __builtin_amdgcn_mfma_f32_16x16x32_bf16(k1, qf[1], z, 0, 0, 0);      \
      }                                                                               \
      __builtin_amdgcn_s_setprio(0);                                                  \
      _Pragma("unroll")                                                               \
      for (int cb = 0; cb < 4; ++cb) {                                                \
        const f32x4 pv = *(const f32x4*)(pmw + li * 64 + (((cb * 4 + g) ^ (li & 7)) << 2)); \
        f32x4 pmc;                                                                    \
        pmc.x = fmaf(pv.x + MCUR[cb].x, LOG2E, -MSHIFT_);                             \
        pmc.y = fmaf(pv.y + MCUR[cb].y, LOG2E, -MSHIFT_);                             \
        pmc.z = fmaf(pv.z + MCUR[cb].z, LOG2E, -MSHIFT_);                             \
        pmc.w = fmaf(pv.w + MCUR[cb].w, LOG2E, -MSHIFT_);                             \
        const float e0 = exp2f(sa[cb][0] + pmc.x);                                    \
        const float e1 = exp2f(sa[cb][1] + pmc.y);                                    \
        const float e2 = exp2f(sa[cb][2] + pmc.z);                                    \
        const float e3 = exp2f(sa[cb][3] + pmc.w);                                    \
        lrun += (e0 + e1) + (e2 + e3);                                                \
        ushort4 pw;                                                                   \
        pw.x = f2b(e0); pw.y = f2b(e1); pw.z = f2b(e2); pw.w = f2b(e3);               \
        *(ushort4*)&p_lds[wv][li][cb * 16 + g * 4] = pw;                              \
      }                                                                               \
      bf16x8 pf0 = *(const bf16x8*)&p_lds[wv][li][g * 8];                             \
      bf16x8 pf1 = *(const bf16x8*)&p_lds[wv][li][32 + g * 8];                        \
      __builtin_amdgcn_s_setprio(1);                                                  \
      _Pragma("unroll")                                                               \
      for (int d = 0; d < 4; ++d) {                                                   \
        const int r = d * 16 + li;                                                    \
        const bf16x8 v0 = *(const bf16x8*)(vb + r * 64 + ((g ^ (li & 7)) << 3));      \
        const bf16x8 v1 = *(const bf16x8*)(vb + r * 64 + (((4 + g) ^ (li & 7)) << 3)); \
        ctx[d] = __builtin_amdgcn_mfma_f32_16x16x32_bf16(pf0, v0, ctx[d], 0, 0, 0);   \
        ctx[d] = __builtin_amdgcn_mfma_f32_16x16x32_bf16(pf1, v1, ctx[d], 0, 0, 0);   \
      }                                                                               \
      __builtin_amdgcn_s_setprio(0);                                                  \
    }                                                                                 \
    __builtin_amdgcn_s_barrier();                                                     \
  }

  for (int t = 0; t < 16; t += 2) {
    PHASE(t,     0, 1, mA, mB);
    PHASE(t + 1, 1, 0, mB, mA);
  }
#undef PHASE
#undef STAGE

  // drain the redundant tail STAGE before LDS deallocation at wave exit
  asm volatile("s_waitcnt vmcnt(0)" ::: "memory");

  // row sums: combine the 4 g-groups (lane li holds partial for q-row li)
  lrun += __shfl_xor(lrun, 16);
  lrun += __shfl_xor(lrun, 32);
#pragma unroll
  for (int j2 = 0; j2 < 4; ++j2) {
    const float rs = __shfl(lrun, g * 4 + j2);
    const float inv = 1.0f / rs;
    const int q = q0 + g * 4 + j2;
    float* op = out + ((size_t)b * S_ + q) * D_ + h * HD_ + li;
#pragma unroll
    for (int d = 0; d < 4; ++d)
      op[d * 16] = ctx[d][j2] * inv;
  }
}

extern "C" void kernel_launch(void* const* d_in, const int* in_sizes, int n_in,
                              void* d_out, int out_size, void* d_ws, size_t ws_size,
                              hipStream_t stream) {
  const float* hs   = (const float*)d_in[0];
  const float* mask = (const float*)d_in[1];
  const float* prev = (const float*)d_in[2];
  const float* Wq   = (const float*)d_in[3];
  const float* bq   = (const float*)d_in[4];
  const float* Wk   = (const float*)d_in[5];
  const float* bk   = (const float*)d_in[6];
  const float* Wv   = (const float*)d_in[7];
  const float* bv   = (const float*)d_in[8];
  float* out = (float*)d_out;

  char* ws = (char*)d_ws;
  unsigned short* Xbf = (unsigned short*)ws;                    // 16 MB
  unsigned short* Wt  = (unsigned short*)(ws + (16ull << 20));  //  6 MB
  unsigned short* Qw  = (unsigned short*)(ws + (22ull << 20));  // 16 MB
  unsigned short* Kw  = (unsigned short*)(ws + (38ull << 20));  // 16 MB
  unsigned short* Vt  = (unsigned short*)(ws + (54ull << 20));  // 16 MB  (total 70 MB)

  k_convert_x<<<2048, 256, 0, stream>>>(hs, Xbf);
  k_transpose_w<<<dim3(16, 16, 3), 256, 0, stream>>>(Wq, Wk, Wv, Wt);
  k_proj<<<dim3(64, 24), 256, 0, stream>>>(Xbf, Wt, bq, bk, bv, Qw, Kw, Vt);
  k_attn<<<dim3(16, 128), 256, 0, stream>>>(Qw, Kw, Vt, prev, mask, out);
}

// Round 21
// 267.245 us; speedup vs baseline: 1.1190x; 1.0154x over previous
//
#include <hip/hip_runtime.h>

#define B_  8
#define S_  1024
#define D_  1024
#define H_  16
#define HD_ 64
#define M_  8192           // B*S
#define LOG2E 1.44269504088896f
#define QSCALE_ (0.125f * 1.44269504088896f)   // fold scale*log2e into Q
#define MSHIFT_ 20.0f      // static softmax shift (log2 domain)

typedef __attribute__((ext_vector_type(8))) short bf16x8;
typedef __attribute__((ext_vector_type(4))) float f32x4;

__device__ __forceinline__ unsigned short f2b(float x) {
  union { float f; unsigned u; } un; un.f = x;
  unsigned r = un.u + 0x7FFFu + ((un.u >> 16) & 1u);  // RNE
  return (unsigned short)(r >> 16);
}

// ---------------- kernel 0: hidden_states f32 -> bf16 ----------------
__global__ __launch_bounds__(256) void k_convert_x(const float* __restrict__ x,
                                                   unsigned short* __restrict__ o) {
  int i = (blockIdx.x * 256 + threadIdx.x) * 4;
  const int n = M_ * D_;
  const int stride = gridDim.x * 256 * 4;
  for (; i < n; i += stride) {
    const float4 v = *(const float4*)(x + i);
    ushort4 r;
    r.x = f2b(v.x); r.y = f2b(v.y); r.z = f2b(v.z); r.w = f2b(v.w);
    *(ushort4*)(o + i) = r;
  }
}

// ---------------- kernel 1: W (K x N) -> Wt bf16 (N x K), 3 matrices ----------------
__global__ __launch_bounds__(256) void k_transpose_w(const float* __restrict__ Wq,
    const float* __restrict__ Wk, const float* __restrict__ Wv,
    unsigned short* __restrict__ Wt) {
  __shared__ float t[64][65];
  const float* W = (blockIdx.z == 0) ? Wq : ((blockIdx.z == 1) ? Wk : Wv);
  unsigned short* dst = Wt + (size_t)blockIdx.z * (D_ * D_);
  const int k0 = blockIdx.x * 64, n0 = blockIdx.y * 64;
  const int tid = threadIdx.x;
#pragma unroll
  for (int i = 0; i < 16; ++i) {
    const int lin = i * 256 + tid;
    const int r = lin >> 6, c = lin & 63;
    t[r][c] = W[(size_t)(k0 + r) * D_ + n0 + c];
  }
  __syncthreads();
#pragma unroll
  for (int i = 0; i < 16; ++i) {
    const int lin = i * 256 + tid;
    const int r = lin >> 6, c = lin & 63;
    dst[(size_t)(n0 + r) * D_ + k0 + c] = f2b(t[c][r]);
  }
}

// ---------------- kernel 2: merged projection GEMM (m97 structure, 128x128x32) ----------------
__global__ __launch_bounds__(256) void k_proj(const unsigned short* __restrict__ X,
    const unsigned short* __restrict__ Wt,
    const float* __restrict__ bq, const float* __restrict__ bk, const float* __restrict__ bv,
    unsigned short* __restrict__ Qw, unsigned short* __restrict__ Kw,
    unsigned short* __restrict__ Vt) {
  __shared__ unsigned short xs[128 * 32];
  __shared__ unsigned short wsh[128 * 32];
  const int tid = threadIdx.x;
  const int lane = tid & 63, wv = tid >> 6;
  const int g = lane >> 4, li = lane & 15;
  const int m0 = blockIdx.x * 128;
  const int mode = (blockIdx.y >= 16);
  const int n0 = (mode ? (blockIdx.y - 16) : blockIdx.y) * 128;
  const int wr = wv >> 1, wc = wv & 1;
  const int wtrow0 = mode ? (2048 + n0) : n0;

  f32x4 acc[4][4];
#pragma unroll
  for (int i = 0; i < 4; ++i)
#pragma unroll
    for (int j = 0; j < 4; ++j) acc[i][j] = (f32x4){0.f, 0.f, 0.f, 0.f};

  const int srow = wv * 32 + (lane >> 2);
  const int skel = (lane & 3) * 8;

  for (int k0 = 0; k0 < D_; k0 += 32) {
#pragma unroll
    for (int i = 0; i < 2; ++i) {
      const unsigned short* gx = X + (size_t)(m0 + srow + i * 16) * D_ + k0 + skel;
      const unsigned short* gw = Wt + (size_t)(wtrow0 + srow + i * 16) * D_ + k0 + skel;
      __builtin_amdgcn_global_load_lds(
          (const __attribute__((address_space(1))) void*)gx,
          (__attribute__((address_space(3))) void*)&xs[(wv * 32 + i * 16) * 32], 16, 0, 0);
      __builtin_amdgcn_global_load_lds(
          (const __attribute__((address_space(1))) void*)gw,
          (__attribute__((address_space(3))) void*)&wsh[(wv * 32 + i * 16) * 32], 16, 0, 0);
    }
    __syncthreads();
    bf16x8 af[4], bfr[4];
#pragma unroll
    for (int i = 0; i < 4; ++i) {
      const int ar = wr * 64 + i * 16 + li;
      const int br = wc * 64 + i * 16 + li;
      if (!mode) {
        af[i]  = *(const bf16x8*)&xs[ar * 32 + g * 8];
        bfr[i] = *(const bf16x8*)&wsh[br * 32 + g * 8];
      } else {
        af[i]  = *(const bf16x8*)&wsh[ar * 32 + g * 8];
        bfr[i] = *(const bf16x8*)&xs[br * 32 + g * 8];
      }
    }
#pragma unroll
    for (int i = 0; i < 4; ++i)
#pragma unroll
      for (int j = 0; j < 4; ++j)
        acc[i][j] = __builtin_amdgcn_mfma_f32_16x16x32_bf16(af[i], bfr[j], acc[i][j], 0, 0, 0);
    __syncthreads();
  }

  if (!mode) {
#pragma unroll
    for (int j = 0; j < 4; ++j) {
      const int n = n0 + wc * 64 + j * 16 + li;
      const float bias = (n < D_) ? bq[n] : bk[n - D_];
#pragma unroll
      for (int i = 0; i < 4; ++i) {
#pragma unroll
        for (int r = 0; r < 4; ++r) {
          const int m = m0 + wr * 64 + i * 16 + g * 4 + r;
          const float v = acc[i][j][r] + bias;
          const int bb = m >> 10, ss = m & 1023;
          if (n < D_) {
            Qw[((size_t)(bb * H_ + (n >> 6)) * S_ + ss) * HD_ + (n & 63)] = f2b(v * QSCALE_);
          } else {
            const int nk = n - D_;
            Kw[((size_t)(bb * H_ + (nk >> 6)) * S_ + ss) * HD_ + (nk & 63)] = f2b(v);
          }
        }
      }
    }
  } else {
#pragma unroll
    for (int i = 0; i < 4; ++i) {
#pragma unroll
      for (int r = 0; r < 4; ++r) {
        const int nv = n0 + wr * 64 + i * 16 + g * 4 + r;
        const float bias = bv[nv];
#pragma unroll
        for (int j = 0; j < 4; ++j) {
          const int m = m0 + wc * 64 + j * 16 + li;
          const int bb = m >> 10, ss = m & 1023;
          const float v = acc[i][j][r] + bias;
          Vt[((size_t)(bb * H_ + (nv >> 6)) * HD_ + (nv & 63)) * S_ + ss] = f2b(v);
        }
      }
    }
  }
}

// ---------------- kernel 3: flash attention, R7 dbuf/vmcnt pipeline + contiguous DMA ----------------
// KVBLK=64, 16 phases, counted vmcnt(12), 2 barriers/phase. DMA footprints contiguous:
// K/V = 1KB over 8 consecutive rows (XOR-permuted within rows), prev = 4 rows x 256B
// runs into a row-major XOR-swizzled pm layout (bank-uniform on the exp read).
__global__ __launch_bounds__(256, 2) void k_attn(const unsigned short* __restrict__ Qw,
    const unsigned short* __restrict__ Kw, const unsigned short* __restrict__ Vt,
    const float* __restrict__ prev, const float* __restrict__ mask,
    float* __restrict__ out) {
  __shared__ unsigned short k_s[2][4096];       // [buf] 64 kv x 64 d, swizzled chunks, 8 KB/buf
  __shared__ unsigned short v_s[2][4096];       // [buf] 64 d x 64 kv, swizzled chunks, 8 KB/buf
  __shared__ float pm_s[2][4][1024];            // [buf][wave] 16 q x 64 kv f32, swizzled, 16 KB/buf
  __shared__ unsigned short p_lds[4][16][72];   // P bounce (q-row major), 144B rows, 9 KB
  const int tid = threadIdx.x;
  const int lane = tid & 63, wv = tid >> 6;
  const int g = lane >> 4, li = lane & 15;

  const int phys = blockIdx.x + 16 * blockIdx.y;  // 0..2047
  const int xcd = phys & 7, idx = phys >> 3;
  const int qt = idx & 15;                        // consecutive same-XCD blocks: same bh
  const int bh = xcd + 8 * (idx >> 4);
  const int b = bh >> 4, h = bh & 15;
  const int q0 = qt * 64 + wv * 16;

  const unsigned short* kbase = Kw + (size_t)bh * S_ * HD_;
  const unsigned short* vbase = Vt + (size_t)bh * HD_ * S_;
  const float* pbase = prev + (size_t)bh * S_ * S_ + (size_t)q0 * S_;  // wave's q-slice
  const float* mb    = mask + (size_t)b * S_ * S_ + (size_t)(q0 + li) * S_ + g * 4;

  // Q fragment (B-operand; col=li=q, k=g*8+e=d), pre-scaled by SCALE*LOG2E
  bf16x8 qf[2];
  {
    const unsigned short* qp = Qw + ((size_t)bh * S_ + q0 + li) * HD_ + g * 8;
    qf[0] = *(const bf16x8*)qp;
    qf[1] = *(const bf16x8*)(qp + 32);
  }

  // K/V DMA: per DMA 8 consecutive rows x 128B (1KB contiguous); lane l -> row
  // group rloc8 = l>>3, chunk (l&7)^rloc8 (XOR permutes within the row).
  const int rloc8 = lane >> 3;
  const int csw8  = (((lane & 7) ^ rloc8) << 3);   // ushort offset of swizzled 16B chunk
  // prev DMA: per DMA 4 rows x 256B; lane l -> row i*4 + (l>>4), chunk (l&15)^(row&7).
  const int prow4 = lane >> 4;
  const int pchnk = lane & 15;

  // 8 global_load_lds + 4 mask VGPR loads per phase per wave = 12 VMEM
#define STAGE(TN, BI)                                                                      \
  {                                                                                        \
    const int sn = (TN) * 64;                                                              \
    _Pragma("unroll")                                                                      \
    for (int i = 0; i < 2; ++i) {                                                          \
      const int row = wv * 16 + i * 8 + rloc8;                                             \
      __builtin_amdgcn_global_load_lds(                                                    \
          (const __attribute__((address_space(1))) void*)(kbase + (size_t)(sn + row) * HD_ + csw8), \
          (__attribute__((address_space(3))) void*)(&k_s[BI][0] + (wv * 16 + i * 8) * 64), 16, 0, 0); \
      __builtin_amdgcn_global_load_lds(                                                    \
          (const __attribute__((address_space(1))) void*)(vbase + (size_t)row * S_ + sn + csw8), \
          (__attribute__((address_space(3))) void*)(&v_s[BI][0] + (wv * 16 + i * 8) * 64), 16, 0, 0); \
    }                                                                                      \
    _Pragma("unroll")                                                                      \
    for (int i = 0; i < 4; ++i) {                                                          \
      const int row = i * 4 + prow4;                                                       \
      __builtin_amdgcn_global_load_lds(                                                    \
          (const __attribute__((address_space(1))) void*)(pbase + (size_t)row * S_ + sn + ((pchnk ^ (row & 7)) << 2)), \
          (__attribute__((address_space(3))) void*)(&pm_s[BI][wv][i * 256]), 16, 0, 0);    \
    }                                                                                      \
  }

  float lrun = 0.f;
  f32x4 ctx[4];
#pragma unroll
  for (int d = 0; d < 4; ++d) ctx[d] = (f32x4){0.f, 0.f, 0.f, 0.f};

  f32x4 mA[4], mB[4];

  // prologue: stage tile 0 + mask(0)  (12 VMEM ops, not waited here)
  STAGE(0, 0);
#pragma unroll
  for (int cb = 0; cb < 4; ++cb) mA[cb] = *(const f32x4*)(mb + cb * 16);

  // Phase: STAGE(t+1,NB) + mask(t+1) [12 ops] -> vmcnt(12) [prev phase's 12 done,
  // current 12 stay in flight] -> barrier -> compute(buf PB, MCUR) -> barrier (WAR).
#define PHASE(T, PB, NB, MCUR, MNXT)                                                  \
  {                                                                                   \
    const int tn = ((T) < 15) ? (T) + 1 : 15;                                         \
    STAGE(tn, NB);                                                                    \
    _Pragma("unroll")                                                                 \
    for (int cb = 0; cb < 4; ++cb)                                                    \
      MNXT[cb] = *(const f32x4*)(mb + tn * 64 + cb * 16);                             \
    asm volatile("s_waitcnt vmcnt(12)" ::: "memory");                                 \
    __builtin_amdgcn_s_barrier();                                                     \
    {                                                                                 \
      const unsigned short* kb = &k_s[PB][0];                                         \
      const unsigned short* vb = &v_s[PB][0];                                         \
      const float* pmw = &pm_s[PB][wv][0];                                            \
      f32x4 sa[4];                                                                    \
      _Pragma("unroll")                                                               \
      for (int cb = 0; cb < 4; ++cb) {                                                \
        const int r = cb * 16 + li;                                                   \
        const bf16x8 k0 = *(const bf16x8*)(kb + r * 64 + ((g ^ (li & 7)) << 3));      \
        const bf16x8 k1 = *(const bf16x8*)(kb + r * 64 + (((4 + g) ^ (li & 7)) << 3)); \
        f32x4 z = (f32x4){0.f, 0.f, 0.f, 0.f};                                        \
        z      = __builtin_amdgcn_mfma_f32_16x16x32_bf16(k0, qf[0], z, 0, 0, 0);      \
        sa[cb] = __builtin_amdgcn_mfma_f32_16x16x32_bf16(k1, qf[1], z, 0, 0, 0);      \
      }                                                                               \
      _Pragma("unroll")                                                               \
      for (int cb = 0; cb < 4; ++cb) {                                                \
        const f32x4 pv = *(const f32x4*)(pmw + li * 64 + (((cb * 4 + g) ^ (li & 7)) << 2)); \
        f32x4 pmc;                                                                    \
        pmc.x = fmaf(pv.x + MCUR[cb].x, LOG2E, -MSHIFT_);                             \
        pmc.y = fmaf(pv.y + MCUR[cb].y, LOG2E, -MSHIFT_);                             \
        pmc.z = fmaf(pv.z + MCUR[cb].z, LOG2E, -MSHIFT_);                             \
        pmc.w = fmaf(pv.w + MCUR[cb].w, LOG2E, -MSHIFT_);                             \
        const float e0 = exp2f(sa[cb][0] + pmc.x);                                    \
        const float e1 = exp2f(sa[cb][1] + pmc.y);                                    \
        const float e2 = exp2f(sa[cb][2] + pmc.z);                                    \
        const float e3 = exp2f(sa[cb][3] + pmc.w);                                    \
        lrun += (e0 + e1) + (e2 + e3);                                                \
        ushort4 pw;                                                                   \
        pw.x = f2b(e0); pw.y = f2b(e1); pw.z = f2b(e2); pw.w = f2b(e3);               \
        *(ushort4*)&p_lds[wv][li][cb * 16 + g * 4] = pw;                              \
      }                                                                               \
      bf16x8 pf0 = *(const bf16x8*)&p_lds[wv][li][g * 8];                             \
      bf16x8 pf1 = *(const bf16x8*)&p_lds[wv][li][32 + g * 8];                        \
      _Pragma("unroll")                                                               \
      for (int d = 0; d < 4; ++d) {                                                   \
        const int r = d * 16 + li;                                                    \
        const bf16x8 v0 = *(const bf16x8*)(vb + r * 64 + ((g ^ (li & 7)) << 3));      \
        const bf16x8 v1 = *(const bf16x8*)(vb + r * 64 + (((4 + g) ^ (li & 7)) << 3)); \
        ctx[d] = __builtin_amdgcn_mfma_f32_16x16x32_bf16(pf0, v0, ctx[d], 0, 0, 0);   \
        ctx[d] = __builtin_amdgcn_mfma_f32_16x16x32_bf16(pf1, v1, ctx[d], 0, 0, 0);   \
      }                                                                               \
    }                                                                                 \
    __builtin_amdgcn_s_barrier();                                                     \
  }

  for (int t = 0; t < 16; t += 2) {
    PHASE(t,     0, 1, mA, mB);
    PHASE(t + 1, 1, 0, mB, mA);
  }
#undef PHASE
#undef STAGE

  // drain the redundant tail STAGE before LDS deallocation at wave exit
  asm volatile("s_waitcnt vmcnt(0)" ::: "memory");

  // row sums: combine the 4 g-groups (lane li holds partial for q-row li)
  lrun += __shfl_xor(lrun, 16);
  lrun += __shfl_xor(lrun, 32);
#pragma unroll
  for (int j2 = 0; j2 < 4; ++j2) {
    const float rs = __shfl(lrun, g * 4 + j2);
    const float inv = 1.0f / rs;
    const int q = q0 + g * 4 + j2;
    float* op = out + ((size_t)b * S_ + q) * D_ + h * HD_ + li;
#pragma unroll
    for (int d = 0; d < 4; ++d)
      op[d * 16] = ctx[d][j2] * inv;
  }
}

extern "C" void kernel_launch(void* const* d_in, const int* in_sizes, int n_in,
                              void* d_out, int out_size, void* d_ws, size_t ws_size,
                              hipStream_t stream) {
  const float* hs   = (const float*)d_in[0];
  const float* mask = (const float*)d_in[1];
  const float* prev = (const float*)d_in[2];
  const float* Wq   = (const float*)d_in[3];
  const float* bq   = (const float*)d_in[4];
  const float* Wk   = (const float*)d_in[5];
  const float* bk   = (const float*)d_in[6];
  const float* Wv   = (const float*)d_in[7];
  const float* bv   = (const float*)d_in[8];
  float* out = (float*)d_out;

  char* ws = (char*)d_ws;
  unsigned short* Xbf = (unsigned short*)ws;                    // 16 MB
  unsigned short* Wt  = (unsigned short*)(ws + (16ull << 20));  //  6 MB
  unsigned short* Qw  = (unsigned short*)(ws + (22ull << 20));  // 16 MB
  unsigned short* Kw  = (unsigned short*)(ws + (38ull << 20));  // 16 MB
  unsigned short* Vt  = (unsigned short*)(ws + (54ull << 20));  // 16 MB  (total 70 MB)

  k_convert_x<<<2048, 256, 0, stream>>>(hs, Xbf);
  k_transpose_w<<<dim3(16, 16, 3), 256, 0, stream>>>(Wq, Wk, Wv, Wt);
  k_proj<<<dim3(64, 24), 256, 0, stream>>>(Xbf, Wt, bq, bk, bv, Qw, Kw, Vt);
  k_attn<<<dim3(16, 128), 256, 0, stream>>>(Qw, Kw, Vt, prev, mask, out);
}